// Round 1
// baseline (80.586 us; speedup 1.0000x reference)
//
#include <hip/hip_runtime.h>

#define RES 96
#define CENTER 48
#define NPIX (RES * RES)
#define EPSF 1e-5f

// One wave (64 lanes) per output pixel. Each lane strides the 9216 sources by
// 64, accumulating w / (d2 + z^2); wave shuffle-reduce; lane 0 writes.
// Rim pixels (r^2 >= 47^2, exact integer test) pass the boundary through.
__global__ __launch_bounds__(64) void topos_kernel(const float* __restrict__ src,
                                                   float* __restrict__ out) {
    const int pix = blockIdx.x;
    const int i = pix / RES;
    const int j = pix - i * RES;
    const int lane = threadIdx.x;  // 0..63

    const int di0 = i - CENTER;
    const int dj0 = j - CENTER;
    const int r2i = di0 * di0 + dj0 * dj0;

    if (r2i >= (CENTER - 1) * (CENTER - 1)) {
        // rim: pass boundary value through (wave-uniform branch)
        if (lane == 0) out[pix] = src[pix];
        return;
    }

    const float r = sqrtf((float)r2i);
    const float z = (float)CENTER - r + EPSF;
    const float z2 = z * z;
    const float fj = (float)j;

    // lane handles sources s = lane, lane+64, ...; track (bi,bj) incrementally
    int bi = 0;
    int bj = lane;  // lane < 96, so initial bi = 0
    float acc = 0.0f;

    #pragma unroll 4
    for (int it = 0; it < NPIX / 64; ++it) {
        const int s = it * 64 + lane;
        const float b = src[s];
        const float wv = b > 0.0f ? b : 0.0f;
        const float fdi = (float)(i - bi);
        const float fdj = fj - (float)bj;
        // denom = d2 + z^2  (the 2*eps*sqrt(d2)+eps^2 terms are <=1e-5 relative)
        const float denom = fmaf(fdj, fdj, fmaf(fdi, fdi, z2));
        acc = fmaf(wv, __builtin_amdgcn_rcpf(denom), acc);
        // advance source coordinates by 64 (at most one row wrap since 64 < 96)
        bj += 64;
        if (bj >= RES) { bj -= RES; bi += 1; }
    }

    // wave reduction across 64 lanes
    #pragma unroll
    for (int off = 32; off > 0; off >>= 1)
        acc += __shfl_down(acc, off, 64);

    if (lane == 0) out[pix] = acc;
}

extern "C" void kernel_launch(void* const* d_in, const int* in_sizes, int n_in,
                              void* d_out, int out_size, void* d_ws, size_t ws_size,
                              hipStream_t stream) {
    const float* src = (const float*)d_in[0];
    float* out = (float*)d_out;
    topos_kernel<<<NPIX, 64, 0, stream>>>(src, out);
}

// Round 3
// 68.688 us; speedup vs baseline: 1.1732x; 1.1732x over previous
//
#include <hip/hip_runtime.h>

#define RES 96
#define CENTER 48
#define NPIX (RES * RES)
#define EPSF 1e-5f

// 4 pixels per 256-thread block (one wave each) -> grid = NPIX/4 = 2304 blocks.
// (R2 bug: launched /64 too few blocks.)
// Each lane processes quads of 4 consecutive sources: s = it*256 + lane*4
// (coalesced float4 loads). All quad starts are multiples of 4 and 96 % 4 == 0,
// so a quad never straddles a row wrap -> coordinate bookkeeping is per-quad.
// One reciprocal per 4 pairs: w0/d0+w1/d1+w2/d2+w3/d3 = num/(d0 d1 d2 d3).
__global__ __launch_bounds__(256) void topos_kernel(const float* __restrict__ src,
                                                    float* __restrict__ out) {
    const int wave = threadIdx.x >> 6;
    const int lane = threadIdx.x & 63;
    const int pix = blockIdx.x * 4 + wave;
    const int i = pix / RES;
    const int j = pix - i * RES;

    const int di0 = i - CENTER;
    const int dj0 = j - CENTER;
    const int r2i = di0 * di0 + dj0 * dj0;

    if (r2i >= (CENTER - 1) * (CENTER - 1)) {
        // rim: pass boundary value through (wave-uniform branch)
        if (lane == 0) out[pix] = src[pix];
        return;
    }

    const float r = sqrtf((float)r2i);
    const float z = (float)CENTER - r + EPSF;
    const float z2 = z * z;

    // lane's first quad: source index s0 = lane*4  (s0 in [0,252])
    const int s0 = lane * 4;
    const int bi0 = s0 / RES;              // 0..2, one-time int div
    const int bj0 = s0 - bi0 * RES;
    float fdi = (float)(i - bi0);
    float fdj = (float)(j - bj0);
    const float wraplim = (float)(j - 95); // fdj < wraplim  <=>  bj > 95
    const float* p = src + s0;

    float acc = 0.0f;

    #pragma unroll 4
    for (int it = 0; it < NPIX / 256; ++it) {   // 36 iterations
        const float4 b4 = *(const float4*)p;
        p += 256;

        const float w0 = fmaxf(b4.x, 0.0f);
        const float w1 = fmaxf(b4.y, 0.0f);
        const float w2 = fmaxf(b4.z, 0.0f);
        const float w3 = fmaxf(b4.w, 0.0f);

        const float t = fmaf(fdi, fdi, z2);     // di^2 + z^2, shared by the quad
        const float u1 = fdj - 1.0f;
        const float u2 = fdj - 2.0f;
        const float u3 = fdj - 3.0f;
        const float d0 = fmaf(fdj, fdj, t);
        const float d1 = fmaf(u1, u1, t);
        const float d2 = fmaf(u2, u2, t);
        const float d3 = fmaf(u3, u3, t);

        // w0/d0 + w1/d1 + w2/d2 + w3/d3 = num / (d0*d1*d2*d3), one rcp
        const float d01 = d0 * d1;
        const float d23 = d2 * d3;
        const float n01 = fmaf(w0, d1, w1 * d0);
        const float n23 = fmaf(w2, d3, w3 * d2);
        const float num = fmaf(n01, d23, n23 * d01);
        const float den = d01 * d23;
        acc = fmaf(num, __builtin_amdgcn_rcpf(den), acc);

        // advance by 256 sources: bj += 64 (mod 96), bi += 2 (+1 on wrap)
        fdj -= 64.0f;
        const bool wr = fdj < wraplim;
        fdj = wr ? fdj + 96.0f : fdj;
        fdi -= wr ? 3.0f : 2.0f;
    }

    // wave reduction across 64 lanes
    #pragma unroll
    for (int off = 32; off > 0; off >>= 1)
        acc += __shfl_down(acc, off, 64);

    if (lane == 0) out[pix] = acc;
}

extern "C" void kernel_launch(void* const* d_in, const int* in_sizes, int n_in,
                              void* d_out, int out_size, void* d_ws, size_t ws_size,
                              hipStream_t stream) {
    const float* src = (const float*)d_in[0];
    float* out = (float*)d_out;
    topos_kernel<<<NPIX / 4, 256, 0, stream>>>(src, out);
}